// Round 11
// baseline (59.075 us; speedup 1.0000x reference)
//
#include <hip/hip_runtime.h>
#include <math.h>

#define NB 64
#define NQ 900
#define NC 91
#define TB_THR 0.9f
#define TC_THR 0.2f
#define EPSF 1e-9f
#define LGEPS 1e-6f

#define TPB 256
#define TPB_S 1024
#define SLOTB 256                   // max KL candidates per batch
#define SP_BLOCKS 225               // 900 waves @ 4/block
#define OUT4_BLOCKS 5344            // ceil(1368000/256)

// ---------------- union-find on LDS (lock-free, min-index root) -------------
__device__ __forceinline__ int ufl_find(int* p, int x) {
    volatile int* vp = (volatile int*)p;
    int px = vp[x];
    while (px != x) { x = px; px = vp[x]; }
    return x;
}

__device__ void ufl_unite(int* p, int a, int b) {
    while (true) {
        a = ufl_find(p, a);
        b = ufl_find(p, b);
        if (a == b) return;
        int hi = a > b ? a : b;
        int lo = a ^ b ^ hi;
        if (atomicCAS(&p[hi], hi, lo) == hi) return;
        a = hi; b = lo;
    }
}

// ---------------- exact GIoU test (cheap necessary gate first) --------------
__device__ __forceinline__ bool pair_test(float4 R, float ai, float4 B, float aj) {
    float ltx = fmaxf(R.x, B.x), lty = fmaxf(R.y, B.y);
    float rbx = fminf(R.z, B.z), rby = fminf(R.w, B.w);
    float w = fmaxf(rbx - ltx, 0.f), h = fmaxf(rby - lty, 0.f);
    float inter = w * h;
    float uni = ai + aj - inter;
    if (!(inter > TB_THR * (uni + EPSF))) return false;   // iou>0.9 necessary gate
    float ex = fmaxf(fmaxf(R.z, B.z) - fminf(R.x, B.x), 0.f);
    float ey = fmaxf(fmaxf(R.w, B.w) - fminf(R.y, B.y), 0.f);
    float ae = ex * ey;
    float iou = inter / (uni + EPSF);
    float giou = iou - (ae - uni) / (ae + EPSF);
    return giou > TB_THR;
}

// ---------------- D1: per-batch binned sweep + KL + LDS union-find ----------
// label[g] = ((global_root)<<1) | in_multi_component
__global__ __launch_bounds__(TPB_S)
void k_sweep(const float* __restrict__ bboxes, const float* __restrict__ logits,
             int* __restrict__ label) {
    __shared__ float4 xy[NQ];
    __shared__ float  ar[NQ];
    __shared__ short  cellOf[NQ];
    __shared__ int    perm[NQ];
    __shared__ int    cstart[101];
    __shared__ int    coff[128];     // scan buffer / running offsets
    __shared__ int    cnt[100];
    __shared__ int    up[NQ];        // union-find parent (local idx)
    __shared__ unsigned char ef[NQ]; // edge endpoint flag
    __shared__ int    lcnt;
    __shared__ int2   lbuf[SLOTB];

    int b   = blockIdx.x;
    int tid = threadIdx.x;
    const float4* bb = (const float4*)(bboxes + (size_t)b * NQ * 4);

    if (tid < 100) cnt[tid] = 0;
    if (tid == 0) lcnt = 0;
    __syncthreads();

    if (tid < NQ) {
        int i = tid;
        float4 v = bb[i];                       // cx cy w h
        float4 e = make_float4(v.x - 0.5f * v.z, v.y - 0.5f * v.w,
                               v.x + 0.5f * v.z, v.y + 0.5f * v.w);
        xy[i] = e;
        ar[i] = (e.z - e.x) * (e.w - e.y);
        int bx = (int)(v.x * 10.f); bx = bx < 0 ? 0 : (bx > 9 ? 9 : bx);
        int by = (int)(v.y * 10.f); by = by < 0 ? 0 : (by > 9 ? 9 : by);
        int c = by * 10 + bx;
        cellOf[i] = (short)c;
        atomicAdd(&cnt[c], 1);
        up[i] = i;
        ef[i] = 0;
    }
    __syncthreads();

    // inclusive scan of cnt[0..99] (Hillis-Steele in coff)
    if (tid < 100) coff[tid] = cnt[tid];
    __syncthreads();
    for (int off = 1; off < 128; off <<= 1) {
        int v = 0;
        if (tid < 100 && tid >= off) v = coff[tid - off];
        __syncthreads();
        if (tid < 100) coff[tid] += v;
        __syncthreads();
    }
    if (tid < 100) cstart[tid + 1] = coff[tid];
    if (tid == 0) cstart[0] = 0;
    __syncthreads();
    if (tid < 100) coff[tid] = cstart[tid];    // running scatter offsets
    __syncthreads();
    if (tid < NQ) {
        int c = cellOf[tid];
        int pos = atomicAdd(&coff[c], 1);
        perm[pos] = tid;
    }
    __syncthreads();

    // pruned pair sweep: |dcx|<0.1, |dcy|<0.1 necessary => 3x3 neighborhood
    if (tid < NQ) {
        int i = tid;
        float4 R = xy[i]; float ai_ = ar[i];
        int c = cellOf[i], bx = c % 10, by = c / 10;
        int xlo = bx > 0 ? bx - 1 : 0, xhi = bx < 9 ? bx + 1 : 9;
        int ylo = by > 0 ? by - 1 : 0, yhi = by < 9 ? by + 1 : 9;
        for (int yy = ylo; yy <= yhi; ++yy)
        for (int xx = xlo; xx <= xhi; ++xx) {
            int d = yy * 10 + xx;
            int s1 = cstart[d + 1];
            for (int k = cstart[d]; k < s1; ++k) {
                int j = perm[k];
                if (j <= i) continue;
                if (pair_test(R, ai_, xy[j], ar[j])) {
                    int pos = atomicAdd(&lcnt, 1);
                    if (pos < SLOTB) lbuf[pos] = make_int2(i, j);
                }
            }
        }
    }
    __syncthreads();

    // wave-parallel KL over candidates; passing edges -> LDS union-find
    int n = lcnt < SLOTB ? lcnt : SLOTB;
    int wv = tid >> 6, lane = tid & 63;
    int gbase = b * NQ;
    for (int m = wv; m < n; m += 16) {
        int2 pr = lbuf[m];
        const float* li = logits + (size_t)(gbase + pr.x) * NC;
        const float* lj = logits + (size_t)(gbase + pr.y) * NC;
        int c1 = lane + 64;
        bool h1 = (c1 < NC);
        float pi0 = 1.f / (1.f + expf(-li[lane]));
        float pj0 = 1.f / (1.f + expf(-lj[lane]));
        float pi1 = h1 ? 1.f / (1.f + expf(-li[c1])) : 0.f;
        float pj1 = h1 ? 1.f / (1.f + expf(-lj[c1])) : 0.f;
        float si = pi0 + pi1, sj = pj0 + pj1;
        for (int o = 32; o; o >>= 1) { si += __shfl_xor(si, o); sj += __shfl_xor(sj, o); }
        float di = si + EPSF, dj = sj + EPSF;
        float qi0 = pi0 / di, qi1 = pi1 / di, qj0 = pj0 / dj, qj1 = pj1 / dj;
        float lqi0 = logf(qi0 + EPSF), lqj0 = logf(qj0 + EPSF);
        float lqi1 = h1 ? logf(qi1 + EPSF) : 0.f;
        float lqj1 = h1 ? logf(qj1 + EPSF) : 0.f;
        float ei  = qi0 * lqi0 + (h1 ? qi1 * lqi1 : 0.f);
        float ej  = qj0 * lqj0 + (h1 ? qj1 * lqj1 : 0.f);
        float dij = qi0 * lqj0 + (h1 ? qi1 * lqj1 : 0.f);
        float dji = qj0 * lqi0 + (h1 ? qj1 * lqi1 : 0.f);
        for (int o = 32; o; o >>= 1) {
            ei  += __shfl_xor(ei, o);  ej  += __shfl_xor(ej, o);
            dij += __shfl_xor(dij, o); dji += __shfl_xor(dji, o);
        }
        bool edge = ((ei - dij) < TC_THR) || ((ej - dji) < TC_THR);
        if (edge && lane == 0) {
            ef[pr.x] = 1;
            ef[pr.y] = 1;
            ufl_unite(up, pr.x, pr.y);
        }
    }
    __syncthreads();

    // resolve roots (stable after barrier) + label writeback
    if (tid < NQ) {
        int r = tid;
        while (up[r] != r) r = up[r];
        label[gbase + tid] = ((gbase + r) << 1) | (ef[tid] ? 1 : 0);
    }
}

// ---------------- D2: streaming output + parallel sparse multi-clusters -----
__global__ __launch_bounds__(TPB)
void k_out(const float* __restrict__ bboxes, const float* __restrict__ logits,
           const int* __restrict__ label, float* __restrict__ out) {
    const long long NBB  = (long long)NB * NQ * 4;          // 230400
    const long long NTOT = NBB + (long long)NB * NQ * NC;   // 5472000
    const float LO = logf(LGEPS) - log1pf(-LGEPS);          // logit(1e-6)
    const float HI = logf(1.f - LGEPS) - log1pf(-(1.f - LGEPS));
    int bid = blockIdx.x;
    if (bid < SP_BLOCKS) {
        // 900 waves; wave owns rows [wv*64, wv*64+64): find multi-roots
        int wv   = bid * 4 + (threadIdx.x >> 6);
        int lane = threadIdx.x & 63;
        int r0   = wv * 64;
        int r    = r0 + lane;
        int lv   = label[r];
        bool isroot = (lv & 1) && ((lv >> 1) == r);
        unsigned long long mask = __ballot(isroot);
        while (mask) {
            int bit = __ffsll((long long)mask) - 1; mask &= mask - 1;
            int R = r0 + bit;
            int b = R / NQ;
            int base = b * NQ;
            float a0 = 0.f, a1 = 0.f, ab = 0.f;
            int cm = 0;
            for (int it = 0; it < 15; ++it) {
                int row = it * 64 + lane;
                bool mem = (row < NQ) && ((label[base + row] >> 1) == R);
                unsigned long long mm = __ballot(mem);
                cm += __popcll(mm);
                while (mm) {                   // ascending row order: deterministic
                    int mb = __ffsll((long long)mm) - 1; mm &= mm - 1;
                    int gg = base + it * 64 + mb;
                    const float* lg = logits + (size_t)gg * NC;
                    a0 += 1.f / (1.f + expf(-lg[lane]));
                    if (lane + 64 < NC) a1 += 1.f / (1.f + expf(-lg[lane + 64]));
                    if (lane < 4)       ab += bboxes[(size_t)gg * 4 + lane];
                }
            }
            float d = (float)cm;               // >= 2
            if (lane < 4) out[(size_t)R * 4 + lane] = ab / d;
            float v0 = fminf(fmaxf(a0 / d, LGEPS), 1.f - LGEPS);
            out[NBB + (size_t)R * NC + lane] = logf(v0) - log1pf(-v0);
            if (lane + 64 < NC) {
                float v1 = fminf(fmaxf(a1 / d, LGEPS), 1.f - LGEPS);
                out[NBB + (size_t)R * NC + lane + 64] = logf(v1) - log1pf(-v1);
            }
        }
        return;
    }
    long long q4 = (long long)(bid - SP_BLOCKS) * TPB + threadIdx.x;
    if (q4 >= NTOT / 4) return;
    long long idx = q4 * 4;
    if (idx < NBB) {
        int g = (int)(idx >> 2);
        int v = label[g];
        float4 o;
        if (!(v & 1))            o = ((const float4*)bboxes)[g];   // singleton
        else if ((v >> 1) != g)  o = make_float4(0.f, 0.f, 0.f, 0.f);
        else return;                                               // multi-root (sparse wrote)
        ((float4*)out)[q4] = o;
        return;
    }
    long long t = idx - NBB;
    int g0 = (int)(t / NC), g3 = (int)((t + 3) / NC);
    if (g0 == g3) {
        int v = label[g0];
        float4 o;
        if (!(v & 1)) {
            // logit(clip(sigmoid(x))) == clamp(x, LO, HI)
            float4 L = *(const float4*)(logits + t);
            o = make_float4(fminf(fmaxf(L.x, LO), HI), fminf(fmaxf(L.y, LO), HI),
                            fminf(fmaxf(L.z, LO), HI), fminf(fmaxf(L.w, LO), HI));
        } else if ((v >> 1) != g0) o = make_float4(LO, LO, LO, LO);
        else return;
        ((float4*)out)[q4] = o;
    } else {
#pragma unroll
        for (int e = 0; e < 4; ++e) {
            long long te = t + e;
            int g = (int)(te / NC);
            int v = label[g];
            if (!(v & 1))           out[idx + e] = fminf(fmaxf(logits[te], LO), HI);
            else if ((v >> 1) != g) out[idx + e] = LO;
            // multi-root: sparse path wrote
        }
    }
}

extern "C" void kernel_launch(void* const* d_in, const int* in_sizes, int n_in,
                              void* d_out, int out_size, void* d_ws, size_t ws_size,
                              hipStream_t stream) {
    const float* bboxes = (const float*)d_in[0];   // [64,900,4] f32
    const float* logits = (const float*)d_in[1];   // [64,900,91] f32
    float* out = (float*)d_out;
    int* label = (int*)d_ws;                       // 57600 ints

    k_sweep<<<NB, TPB_S, 0, stream>>>(bboxes, logits, label);

    k_out<<<SP_BLOCKS + OUT4_BLOCKS, TPB, 0, stream>>>(bboxes, logits, label, out);
}

// Round 12
// 54.856 us; speedup vs baseline: 1.0769x; 1.0769x over previous
//
#include <hip/hip_runtime.h>
#include <math.h>

#define NB 64
#define NQ 900
#define NC 91
#define TB_THR 0.9f
#define TC_THR 0.2f
#define EPSF 1e-9f
#define LGEPS 1e-6f

#define TPB 256
#define TT 120                      // tile side
#define SUB 60                      // rows per lane-slot (2 rows/thread)
#define TPAIRS 36                   // 8*(8+1)/2 tile pairs per batch
#define EDGE_BLOCKS (NB * TPAIRS)   // 2304
#define INIT_BLOCKS 225             // 57600/256
#define SP_BLOCKS 225               // 900 waves @ 4/block
#define OUT4_BLOCKS 5344            // ceil(1368000/256)
#define SLOT 64                     // max edges per sweep block
#define UNITE_BLOCKS (EDGE_BLOCKS * SLOT / TPB)   // 576

// ---------------- union-find (lock-free, min-index root) --------------------
__device__ __forceinline__ int uf_find(int* p, int x) {
    volatile int* vp = (volatile int*)p;
    int px = vp[x];
    while (px != x) { x = px; px = vp[x]; }
    return x;
}

__device__ void uf_unite(int* p, int a, int b) {
    while (true) {
        a = uf_find(p, a);
        b = uf_find(p, b);
        if (a == b) return;
        int hi = a > b ? a : b;
        int lo = a ^ b ^ hi;
        if (atomicCAS(&p[hi], hi, lo) == hi) return;
        a = hi; b = lo;
    }
}

// ---------------- exact GIoU test (cheap necessary gate first) --------------
__device__ __forceinline__ bool pair_test(float4 R, float ai, float4 B, float aj) {
    float ltx = fmaxf(R.x, B.x), lty = fmaxf(R.y, B.y);
    float rbx = fminf(R.z, B.z), rby = fminf(R.w, B.w);
    float w = fmaxf(rbx - ltx, 0.f), h = fmaxf(rby - lty, 0.f);
    float inter = w * h;
    float uni = ai + aj - inter;
    if (!(inter > TB_THR * (uni + EPSF))) return false;   // iou>0.9 necessary gate
    float ex = fmaxf(fmaxf(R.z, B.z) - fminf(R.x, B.x), 0.f);
    float ey = fmaxf(fmaxf(R.w, B.w) - fminf(R.y, B.y), 0.f);
    float ae = ex * ey;
    float iou = inter / (uni + EPSF);
    float giou = iou - (ae - uni) / (ae + EPSF);
    return giou > TB_THR;
}

// ---------------- wave-parallel KL for ballot-flagged pairs -----------------
__device__ void kl_process(unsigned long long m, int ibase, int j, int gbase,
                           const float* __restrict__ logits, int lane,
                           int* lcnt, int2* lbuf) {
    while (m) {
        int src = __ffsll((long long)m) - 1; m &= m - 1;
        int gi = gbase + ibase + src;
        int gj = gbase + j;
        const float* li = logits + (size_t)gi * NC;
        const float* lj = logits + (size_t)gj * NC;
        int c1 = lane + 64;
        bool h1 = (c1 < NC);
        float pi0 = 1.f / (1.f + expf(-li[lane]));
        float pj0 = 1.f / (1.f + expf(-lj[lane]));
        float pi1 = h1 ? 1.f / (1.f + expf(-li[c1])) : 0.f;
        float pj1 = h1 ? 1.f / (1.f + expf(-lj[c1])) : 0.f;
        float si = pi0 + pi1, sj = pj0 + pj1;
        for (int o = 32; o; o >>= 1) { si += __shfl_xor(si, o); sj += __shfl_xor(sj, o); }
        float di = si + EPSF, dj = sj + EPSF;
        float qi0 = pi0 / di, qi1 = pi1 / di, qj0 = pj0 / dj, qj1 = pj1 / dj;
        float lqi0 = logf(qi0 + EPSF), lqj0 = logf(qj0 + EPSF);
        float lqi1 = h1 ? logf(qi1 + EPSF) : 0.f;
        float lqj1 = h1 ? logf(qj1 + EPSF) : 0.f;
        float ei  = qi0 * lqi0 + (h1 ? qi1 * lqi1 : 0.f);
        float ej  = qj0 * lqj0 + (h1 ? qj1 * lqj1 : 0.f);
        float dij = qi0 * lqj0 + (h1 ? qi1 * lqj1 : 0.f);
        float dji = qj0 * lqi0 + (h1 ? qj1 * lqi1 : 0.f);
        for (int o = 32; o; o >>= 1) {
            ei  += __shfl_xor(ei, o);  ej  += __shfl_xor(ej, o);
            dij += __shfl_xor(dij, o); dji += __shfl_xor(dji, o);
        }
        bool edge = ((ei - dij) < TC_THR) || ((ej - dji) < TC_THR);
        if (edge && lane == 0) {
            int pos = atomicAdd(lcnt, 1);
            if (pos < SLOT) lbuf[pos] = make_int2(gi, gj);
        }
    }
}

// ---------------- D1: GIoU sweep + fused KL -> per-block edge slots ---------
__global__ __launch_bounds__(TPB)
void k_sweep(const float* __restrict__ bboxes, const float* __restrict__ logits,
             int* __restrict__ parent, int* __restrict__ ovl,
             int* __restrict__ bcnt, int2* __restrict__ slots) {
    __shared__ float4 jb[TT];
    __shared__ float  ja[TT];
    __shared__ int lcnt;
    __shared__ int2 lbuf[SLOT];
    int bid = blockIdx.x;
    if (bid >= EDGE_BLOCKS) {
        int idx = (bid - EDGE_BLOCKS) * TPB + threadIdx.x;
        if (idx < NB * NQ) { parent[idx] = idx; ovl[idx] = 0; }
        return;
    }
    if (threadIdx.x == 0) lcnt = 0;
    int b = bid / TPAIRS, tp = bid % TPAIRS;
    int tj = (int)((sqrtf(8.f * tp + 1.f) - 1.f) * 0.5f);
    while ((tj + 1) * (tj + 2) / 2 <= tp) ++tj;
    while (tj * (tj + 1) / 2 > tp) --tj;
    int ti = tp - tj * (tj + 1) / 2;          // ti <= tj
    int i0 = ti * TT, j0 = tj * TT;
    const float4* bb = (const float4*)(bboxes + (size_t)b * NQ * 4);

    int jend = NQ - j0; if (jend > TT) jend = TT;
    for (int k = threadIdx.x; k < jend; k += TPB) {
        float4 v = bb[j0 + k];                 // cx cy w h
        float4 e = make_float4(v.x - 0.5f * v.z, v.y - 0.5f * v.w,
                               v.x + 0.5f * v.z, v.y + 0.5f * v.w);
        jb[k] = e;
        ja[k] = (e.z - e.x) * (e.w - e.y);
    }
    __syncthreads();

    int lane = threadIdx.x & 63;
    int wv   = threadIdx.x >> 6;
    bool lv  = lane < SUB;
    int iA = i0 + (lv ? lane : 0);
    int iB = iA + SUB;
    bool vB = lv && (iB < NQ);

    float4 a4 = bb[iA];
    float4 RA = make_float4(a4.x - 0.5f * a4.z, a4.y - 0.5f * a4.w,
                            a4.x + 0.5f * a4.z, a4.y + 0.5f * a4.w);
    float aA = (RA.z - RA.x) * (RA.w - RA.y);
    float4 b4 = bb[vB ? iB : iA];
    float4 RB = make_float4(b4.x - 0.5f * b4.z, b4.y - 0.5f * b4.w,
                            b4.x + 0.5f * b4.z, b4.y + 0.5f * b4.w);
    float aB = (RB.z - RB.x) * (RB.w - RB.y);

    int gbase = b * NQ;
    int jlo = wv * 30, jhi = jlo + 30; if (jhi > jend) jhi = jend;
    for (int jj = jlo; jj < jhi; ++jj) {
        int j = j0 + jj;
        float4 B = jb[jj];
        float aj = ja[jj];
        bool fA = lv && (iA < j) && pair_test(RA, aA, B, aj);
        bool fB = vB && (iB < j) && pair_test(RB, aB, B, aj);
        unsigned long long mA = __ballot(fA);
        unsigned long long mB = __ballot(fB);
        if (mA | mB) {                         // rare, wave-uniform
            kl_process(mA, i0, j, gbase, logits, lane, &lcnt, lbuf);
            kl_process(mB, i0 + SUB, j, gbase, logits, lane, &lcnt, lbuf);
        }
    }
    __syncthreads();
    int n = lcnt < SLOT ? lcnt : SLOT;
    if (threadIdx.x == 0) bcnt[bid] = n;
    for (int k = threadIdx.x; k < n; k += TPB) slots[bid * SLOT + k] = lbuf[k];
}

// ---------------- D2: parallel unions, one thread PER EDGE SLOT -------------
__global__ __launch_bounds__(TPB)
void k_unite(int* __restrict__ parent, int* __restrict__ ovl,
             const int* __restrict__ bcnt, const int2* __restrict__ slots) {
    int idx = blockIdx.x * TPB + threadIdx.x;   // 0 .. EDGE_BLOCKS*SLOT
    int blk = idx >> 6;                         // SLOT == 64
    int k   = idx & (SLOT - 1);
    if (blk >= EDGE_BLOCKS) return;
    int c = bcnt[blk]; if (c > SLOT) c = SLOT;  // wave-uniform load
    if (k < c) {
        int2 e = slots[idx];
        uf_unite(parent, e.x, e.y);
        ovl[e.x] = 1;                  // benign race: same value
        ovl[e.y] = 1;
    }
}

// ---------------- D3: streaming output + parallel sparse multi-clusters -----
__global__ __launch_bounds__(TPB)
void k_out(const float* __restrict__ bboxes, const float* __restrict__ logits,
           int* __restrict__ parent, const int* __restrict__ ovl,
           float* __restrict__ out) {
    const long long NBB  = (long long)NB * NQ * 4;          // 230400
    const long long NTOT = NBB + (long long)NB * NQ * NC;   // 5472000
    const float LO = logf(LGEPS) - log1pf(-LGEPS);          // logit(1e-6)
    const float HI = logf(1.f - LGEPS) - log1pf(-(1.f - LGEPS));
    int bid = blockIdx.x;
    if (bid < SP_BLOCKS) {
        // 900 waves; wave wv owns rows [wv*64, wv*64+64): find multi-roots
        int wv   = bid * 4 + (threadIdx.x >> 6);
        int lane = threadIdx.x & 63;
        int r0   = wv * 64;
        int r    = r0 + lane;
        bool inEdge = ovl[r] != 0;
        bool isroot = inEdge && (uf_find(parent, r) == r);
        unsigned long long mask = __ballot(isroot);
        while (mask) {
            int bit = __ffsll((long long)mask) - 1; mask &= mask - 1;
            int R = r0 + bit;
            int b = R / NQ;
            int base = b * NQ;
            float a0 = 0.f, a1 = 0.f, ab = 0.f;
            int cm = 0;
            for (int it = 0; it < 15; ++it) {
                int row = it * 64 + lane;
                int g = base + row;
                bool mem = (row < NQ) && (ovl[g] != 0) && (uf_find(parent, g) == R);
                unsigned long long mm = __ballot(mem);
                cm += __popcll(mm);
                while (mm) {                   // ascending row order: deterministic
                    int mb = __ffsll((long long)mm) - 1; mm &= mm - 1;
                    int gg = base + it * 64 + mb;
                    const float* lg = logits + (size_t)gg * NC;
                    a0 += 1.f / (1.f + expf(-lg[lane]));
                    if (lane + 64 < NC) a1 += 1.f / (1.f + expf(-lg[lane + 64]));
                    if (lane < 4)       ab += bboxes[(size_t)gg * 4 + lane];
                }
            }
            float d = (float)cm;               // >= 2
            if (lane < 4) out[(size_t)R * 4 + lane] = ab / d;
            float v0 = fminf(fmaxf(a0 / d, LGEPS), 1.f - LGEPS);
            out[NBB + (size_t)R * NC + lane] = logf(v0) - log1pf(-v0);
            if (lane + 64 < NC) {
                float v1 = fminf(fmaxf(a1 / d, LGEPS), 1.f - LGEPS);
                out[NBB + (size_t)R * NC + lane + 64] = logf(v1) - log1pf(-v1);
            }
        }
        return;
    }
    long long q4 = (long long)(bid - SP_BLOCKS) * TPB + threadIdx.x;
    if (q4 >= NTOT / 4) return;
    long long idx = q4 * 4;
    if (idx < NBB) {
        int g = (int)(idx >> 2);
        float4 o;
        if (ovl[g] == 0) o = ((const float4*)bboxes)[g];          // singleton
        else if (uf_find(parent, g) != g) o = make_float4(0.f, 0.f, 0.f, 0.f);
        else return;                                              // multi-root (sparse wrote)
        ((float4*)out)[q4] = o;
        return;
    }
    long long t = idx - NBB;
    int g0 = (int)(t / NC), g3 = (int)((t + 3) / NC);
    if (g0 == g3) {
        float4 o;
        if (ovl[g0] == 0) {
            // logit(clip(sigmoid(x))) == clamp(x, LO, HI)
            float4 L = *(const float4*)(logits + t);
            o = make_float4(fminf(fmaxf(L.x, LO), HI), fminf(fmaxf(L.y, LO), HI),
                            fminf(fmaxf(L.z, LO), HI), fminf(fmaxf(L.w, LO), HI));
        } else if (uf_find(parent, g0) != g0) o = make_float4(LO, LO, LO, LO);
        else return;
        ((float4*)out)[q4] = o;
    } else {
#pragma unroll
        for (int e = 0; e < 4; ++e) {
            long long te = t + e;
            int g = (int)(te / NC);
            if (ovl[g] == 0) out[idx + e] = fminf(fmaxf(logits[te], LO), HI);
            else if (uf_find(parent, g) != g) out[idx + e] = LO;
            // multi-root: sparse path wrote
        }
    }
}

extern "C" void kernel_launch(void* const* d_in, const int* in_sizes, int n_in,
                              void* d_out, int out_size, void* d_ws, size_t ws_size,
                              hipStream_t stream) {
    const float* bboxes = (const float*)d_in[0];   // [64,900,4] f32
    const float* logits = (const float*)d_in[1];   // [64,900,91] f32
    float* out = (float*)d_out;

    char* ws = (char*)d_ws;
    const int NROWS = NB * NQ;                     // 57600
    int*  parent = (int*) (ws);
    int*  ovl    = (int*) (ws + 1 * NROWS * 4);
    int*  bcnt   = (int*) (ws + 2 * NROWS * 4);                 // 2304 ints
    int2* slots  = (int2*)(ws + 2 * NROWS * 4 + 16384);         // 8-aligned

    k_sweep<<<EDGE_BLOCKS + INIT_BLOCKS, TPB, 0, stream>>>(
        bboxes, logits, parent, ovl, bcnt, slots);

    k_unite<<<UNITE_BLOCKS, TPB, 0, stream>>>(parent, ovl, bcnt, slots);

    k_out<<<SP_BLOCKS + OUT4_BLOCKS, TPB, 0, stream>>>(bboxes, logits, parent, ovl, out);
}